// Round 9
// baseline (275.967 us; speedup 1.0000x reference)
//
#include <hip/hip_runtime.h>

typedef short s16x8 __attribute__((ext_vector_type(8)));
typedef float f32x4 __attribute__((ext_vector_type(4)));

// bf16 helpers (manual, round-to-nearest-even)
__device__ __forceinline__ unsigned short f2bf(float f) {
  unsigned int u = __float_as_uint(f);
  unsigned int r = (u + 0x7FFFu + ((u >> 16) & 1u)) >> 16;
  return (unsigned short)r;
}
__device__ __forceinline__ float bf_lo(unsigned int u) { return __uint_as_float(u << 16); }
__device__ __forceinline__ float bf_hi(unsigned int u) { return __uint_as_float(u & 0xFFFF0000u); }

// ---------------- degree / CSR build ----------------
// CSR holds REAL edges only (no self-loops), entry = src id (4 B).
// Weights factored out: rows pre-scaled by dinv[s] at producers, sums
// scaled by dinv[d] at consumers; self term added inline (coalesced).

__global__ void k_init_deg(int* __restrict__ deg, int n) {
  int i = blockIdx.x * blockDim.x + threadIdx.x;
  if (i < n) deg[i] = 1;  // self-loop counts toward degree
}

__global__ void k_count(const int* __restrict__ dst, int* __restrict__ deg, int e) {
  int i = blockIdx.x * blockDim.x + threadIdx.x;
  if (i < e) atomicAdd(&deg[dst[i]], 1);
}

__global__ void k_dinv(const int* __restrict__ deg, float* __restrict__ dinv, int n) {
  int i = blockIdx.x * blockDim.x + threadIdx.x;
  if (i < n) dinv[i] = rsqrtf((float)deg[i]);
}

// xs = x * dinv (row-wise pre-scale of input features)
__global__ void k_scalex(const float* __restrict__ x, const float* __restrict__ dinv,
                         float* __restrict__ xs, int n) {
  int i = blockIdx.x * blockDim.x + threadIdx.x;
  if (i < n * 7) xs[i] = x[i] * dinv[i / 7];
}

// scan over real-edge counts (deg-1)
__global__ void k_scan1(const int* __restrict__ deg, int* __restrict__ rp,
                        int* __restrict__ psum, int n) {
  __shared__ int s[256];
  int tid = threadIdx.x;
  int i = blockIdx.x * 256 + tid;
  int v = (i < n) ? deg[i] - 1 : 0;
  int x = v;
  s[tid] = x; __syncthreads();
  for (int off = 1; off < 256; off <<= 1) {
    int t = (tid >= off) ? s[tid - off] : 0;
    __syncthreads();
    x += t; s[tid] = x;
    __syncthreads();
  }
  if (i < n) rp[i] = x - v;                 // exclusive within block
  if (tid == 255) psum[blockIdx.x] = x;     // block total
}

__global__ void k_scan2(int* __restrict__ psum, int nb) {
  __shared__ int s[256];
  int tid = threadIdx.x;
  int v = (tid < nb) ? psum[tid] : 0;
  int x = v;
  s[tid] = x; __syncthreads();
  for (int off = 1; off < 256; off <<= 1) {
    int t = (tid >= off) ? s[tid - off] : 0;
    __syncthreads();
    x += t; s[tid] = x;
    __syncthreads();
  }
  if (tid < nb) psum[tid] = x - v;          // exclusive prefix of block sums
}

__global__ void k_scan3(int* __restrict__ rp, int* __restrict__ cursor,
                        const int* __restrict__ psum, int n, int total) {
  int i = blockIdx.x * blockDim.x + threadIdx.x;
  if (i < n) {
    int r = rp[i] + psum[i >> 8];
    rp[i] = r;
    cursor[i] = r;
  }
  if (i == 0) rp[n] = total;
}

__global__ void k_scatter(const int* __restrict__ src, const int* __restrict__ dst,
                          int* __restrict__ cursor, int* __restrict__ csr, int e) {
  int i = blockIdx.x * blockDim.x + threadIdx.x;
  if (i >= e) return;
  int pos = atomicAdd(&cursor[dst[i]], 1);
  csr[pos] = src[i];
}

// W [K x N] fp32 -> Wt [N x K] bf16 (transposed, for contiguous B-fragment loads)
__global__ void k_wtr(const float* __restrict__ W, unsigned short* __restrict__ Wt,
                      int K, int N) {
  int i = blockIdx.x * blockDim.x + threadIdx.x;
  if (i < K * N) {
    int k = i / N, c = i - k * N;
    Wt[(size_t)c * K + k] = f2bf(W[i]);
  }
}

// ---------------- aggregation (pull, CSR by dst) ----------------

// width-7 aggregation on pre-scaled xs: lane per edge + butterfly reduce.
// out[d] = dinv[d] * (sum_{edges} xs[s] + xs[d])
__global__ void k_agg7(const float* __restrict__ xs, const int* __restrict__ csr,
                       const int* __restrict__ rp, const float* __restrict__ dinv,
                       float* __restrict__ out, int n) {
  int gid = blockIdx.x * blockDim.x + threadIdx.x;
  int v = gid >> 6, lane = gid & 63;
  if (v >= n) return;
  int beg = rp[v], end = rp[v + 1];
  float a[7] = {0.f, 0.f, 0.f, 0.f, 0.f, 0.f, 0.f};
  for (int base = beg; base < end; base += 64) {
    int cnt = end - base; if (cnt > 64) cnt = 64;
    if (lane < cnt) {
      int s = csr[base + lane];
      const float* xr = xs + (size_t)s * 7;
#pragma unroll
      for (int f = 0; f < 7; ++f) a[f] += xr[f];
    }
  }
#pragma unroll
  for (int off = 32; off > 0; off >>= 1) {
#pragma unroll
    for (int f = 0; f < 7; ++f) a[f] += __shfl_xor(a[f], off);
  }
  if (lane == 0) {
    float dv = dinv[v];
#pragma unroll
    for (int f = 0; f < 7; ++f) out[(size_t)v * 7 + f] = dv * (a[f] + xs[(size_t)v * 7 + f]);
  }
}

// width-128 bf16 aggregation: 32 lanes/node, uint2 (4 bf16)/lane.
// fp32 accumulate; out = bf16(dinv[d] * (sum + own_row)).
__global__ void k_agg128(const unsigned short* __restrict__ t, const int* __restrict__ csr,
                         const int* __restrict__ rp, const float* __restrict__ dinv,
                         unsigned short* __restrict__ out, int n) {
  int gid = blockIdx.x * blockDim.x + threadIdx.x;
  int v = gid >> 5, lane = gid & 31;
  if (v >= n) return;
  int beg = rp[v], end = rp[v + 1];
  float4 a = make_float4(0.f, 0.f, 0.f, 0.f);
  const uint2* tp = (const uint2*)t + lane;   // row stride = 32 uint2 (128 bf16)
  for (int base = beg; base < end; base += 32) {
    int cnt = end - base; if (cnt > 32) cnt = 32;
    int ee = csr[base + (lane < cnt ? lane : cnt - 1)];
    int j = 0;
    for (; j + 4 <= cnt; j += 4) {
      int s0 = __shfl(ee, j + 0, 32), s1 = __shfl(ee, j + 1, 32);
      int s2 = __shfl(ee, j + 2, 32), s3 = __shfl(ee, j + 3, 32);
      uint2 r0 = tp[(size_t)s0 * 32];
      uint2 r1 = tp[(size_t)s1 * 32];
      uint2 r2 = tp[(size_t)s2 * 32];
      uint2 r3 = tp[(size_t)s3 * 32];
      a.x += bf_lo(r0.x); a.y += bf_hi(r0.x); a.z += bf_lo(r0.y); a.w += bf_hi(r0.y);
      a.x += bf_lo(r1.x); a.y += bf_hi(r1.x); a.z += bf_lo(r1.y); a.w += bf_hi(r1.y);
      a.x += bf_lo(r2.x); a.y += bf_hi(r2.x); a.z += bf_lo(r2.y); a.w += bf_hi(r2.y);
      a.x += bf_lo(r3.x); a.y += bf_hi(r3.x); a.z += bf_lo(r3.y); a.w += bf_hi(r3.y);
    }
    for (; j < cnt; ++j) {
      int s0 = __shfl(ee, j, 32);
      uint2 r0 = tp[(size_t)s0 * 32];
      a.x += bf_lo(r0.x); a.y += bf_hi(r0.x); a.z += bf_lo(r0.y); a.w += bf_hi(r0.y);
    }
  }
  // self term (coalesced)
  {
    uint2 r = tp[(size_t)v * 32];
    a.x += bf_lo(r.x); a.y += bf_hi(r.x); a.z += bf_lo(r.y); a.w += bf_hi(r.y);
  }
  float dv = dinv[v];
  unsigned int lo = (unsigned int)f2bf(a.x * dv) | ((unsigned int)f2bf(a.y * dv) << 16);
  unsigned int hi = (unsigned int)f2bf(a.z * dv) | ((unsigned int)f2bf(a.w * dv) << 16);
  ((uint2*)(out + (size_t)v * 128))[lane] = make_uint2(lo, hi);
}

// width-64 bf16 aggregation + bias: 16 lanes/node.
// out[d] = dinv[d] * (sum + own_row) + b3  (fp32 out)
__global__ void k_agg64b(const unsigned short* __restrict__ t, const int* __restrict__ csr,
                         const int* __restrict__ rp, const float* __restrict__ dinv,
                         const float* __restrict__ bias, float* __restrict__ out, int n) {
  int gid = blockIdx.x * blockDim.x + threadIdx.x;
  int v = gid >> 4, lane = gid & 15;
  if (v >= n) return;
  int beg = rp[v], end = rp[v + 1];
  float4 a = make_float4(0.f, 0.f, 0.f, 0.f);
  const uint2* tp = (const uint2*)t + lane;   // row stride = 16 uint2 (64 bf16)
  for (int base = beg; base < end; base += 16) {
    int cnt = end - base; if (cnt > 16) cnt = 16;
    int ee = csr[base + (lane < cnt ? lane : cnt - 1)];
    int j = 0;
    for (; j + 4 <= cnt; j += 4) {
      int s0 = __shfl(ee, j + 0, 16), s1 = __shfl(ee, j + 1, 16);
      int s2 = __shfl(ee, j + 2, 16), s3 = __shfl(ee, j + 3, 16);
      uint2 r0 = tp[(size_t)s0 * 16];
      uint2 r1 = tp[(size_t)s1 * 16];
      uint2 r2 = tp[(size_t)s2 * 16];
      uint2 r3 = tp[(size_t)s3 * 16];
      a.x += bf_lo(r0.x); a.y += bf_hi(r0.x); a.z += bf_lo(r0.y); a.w += bf_hi(r0.y);
      a.x += bf_lo(r1.x); a.y += bf_hi(r1.x); a.z += bf_lo(r1.y); a.w += bf_hi(r1.y);
      a.x += bf_lo(r2.x); a.y += bf_hi(r2.x); a.z += bf_lo(r2.y); a.w += bf_hi(r2.y);
      a.x += bf_lo(r3.x); a.y += bf_hi(r3.x); a.z += bf_lo(r3.y); a.w += bf_hi(r3.y);
    }
    for (; j < cnt; ++j) {
      int s0 = __shfl(ee, j, 16);
      uint2 r0 = tp[(size_t)s0 * 16];
      a.x += bf_lo(r0.x); a.y += bf_hi(r0.x); a.z += bf_lo(r0.y); a.w += bf_hi(r0.y);
    }
  }
  // self term (coalesced)
  {
    uint2 r = tp[(size_t)v * 16];
    a.x += bf_lo(r.x); a.y += bf_hi(r.x); a.z += bf_lo(r.y); a.w += bf_hi(r.y);
  }
  float dv = dinv[v];
  const float4 b4 = ((const float4*)bias)[lane];
  a.x = a.x * dv + b4.x; a.y = a.y * dv + b4.y;
  a.z = a.z * dv + b4.z; a.w = a.w * dv + b4.w;
  ((float4*)(out + (size_t)v * 64))[lane] = a;
}

// ---------------- GEMMs ----------------

// [n,7] @ [7,128] + b, relu, then row-scale by dinv -> bf16 out.
__global__ __launch_bounds__(256) void k_gemm1(const float* __restrict__ A,
                                               const float* __restrict__ W,
                                               const float* __restrict__ bias,
                                               const float* __restrict__ dinv,
                                               unsigned short* __restrict__ out, int n) {
  __shared__ float ws[7 * 128];
  for (int j = threadIdx.x; j < 7 * 128; j += 256) ws[j] = W[j];
  __syncthreads();
  int r = blockIdx.x * 2 + (threadIdx.x >> 7);
  int c = threadIdx.x & 127;
  if (r >= n) return;
  const float* a = A + (size_t)r * 7;
  float acc = bias[c];
#pragma unroll
  for (int k = 0; k < 7; ++k) acc += a[k] * ws[k * 128 + c];
  out[(size_t)r * 128 + c] = f2bf(fmaxf(acc, 0.f) * dinv[r]);
}

// MFMA gemm2: [n,128]bf16 @ W2 + b2, relu -> [n,128]bf16. (h2 is NOT pre-scaled:
// it feeds gemm3 directly, not an aggregation.)
__global__ __launch_bounds__(256) void k_gemm2(const unsigned short* __restrict__ A,
                                               const unsigned short* __restrict__ Bt,
                                               const float* __restrict__ bias,
                                               unsigned short* __restrict__ out, int n) {
  int wave = threadIdx.x >> 6, lane = threadIdx.x & 63;
  int am = lane & 15, kg = lane >> 4;
  int r0 = blockIdx.x * 64 + wave * 16;
  int arow = min(r0 + am, n - 1);
  const unsigned short* ap = A + (size_t)arow * 128 + kg * 8;
  f32x4 acc[8] = {};
#pragma unroll
  for (int kb = 0; kb < 4; ++kb) {
    s16x8 a = *(const s16x8*)(ap + kb * 32);
#pragma unroll
    for (int c = 0; c < 8; ++c) {
      s16x8 b = *(const s16x8*)(Bt + (size_t)(c * 16 + am) * 128 + kb * 32 + kg * 8);
      acc[c] = __builtin_amdgcn_mfma_f32_16x16x32_bf16(a, b, acc[c], 0, 0, 0);
    }
  }
#pragma unroll
  for (int c = 0; c < 8; ++c) {
    float bb = bias[c * 16 + am];
#pragma unroll
    for (int j = 0; j < 4; ++j) {
      int r = r0 + kg * 4 + j;
      if (r < n) out[(size_t)r * 128 + c * 16 + am] = f2bf(fmaxf(acc[c][j] + bb, 0.f));
    }
  }
}

// MFMA gemm3: [n,128]bf16 @ W3, row-scale by dinv -> [n,64]bf16 (feeds agg64b).
__global__ __launch_bounds__(256) void k_gemm3(const unsigned short* __restrict__ A,
                                               const unsigned short* __restrict__ Bt,
                                               const float* __restrict__ dinv,
                                               unsigned short* __restrict__ out, int n) {
  int wave = threadIdx.x >> 6, lane = threadIdx.x & 63;
  int am = lane & 15, kg = lane >> 4;
  int r0 = blockIdx.x * 64 + wave * 16;
  int arow = min(r0 + am, n - 1);
  const unsigned short* ap = A + (size_t)arow * 128 + kg * 8;
  f32x4 acc[4] = {};
#pragma unroll
  for (int kb = 0; kb < 4; ++kb) {
    s16x8 a = *(const s16x8*)(ap + kb * 32);
#pragma unroll
    for (int c = 0; c < 4; ++c) {
      s16x8 b = *(const s16x8*)(Bt + (size_t)(c * 16 + am) * 128 + kb * 32 + kg * 8);
      acc[c] = __builtin_amdgcn_mfma_f32_16x16x32_bf16(a, b, acc[c], 0, 0, 0);
    }
  }
  float dv[4];
#pragma unroll
  for (int j = 0; j < 4; ++j) dv[j] = dinv[min(r0 + kg * 4 + j, n - 1)];
#pragma unroll
  for (int c = 0; c < 4; ++c) {
#pragma unroll
    for (int j = 0; j < 4; ++j) {
      int r = r0 + kg * 4 + j;
      if (r < n) out[(size_t)r * 64 + c * 16 + am] = f2bf(acc[c][j] * dv[j]);
    }
  }
}

// ---------------- mean pool over sorted batch (node-parallel) ----------------

__global__ void k_zero(float* __restrict__ p, int n) {
  int i = blockIdx.x * blockDim.x + threadIdx.x;
  if (i < n) p[i] = 0.f;
}

__global__ void k_pool1(const float* __restrict__ h, const int* __restrict__ batch,
                        float* __restrict__ sums, int n) {
  int gid = blockIdx.x * blockDim.x + threadIdx.x;
  int w = gid >> 6, f = gid & 63;
  int i0 = w * 16;
  if (i0 >= n) return;
  int i1 = min(i0 + 16, n);
  int cur = batch[i0];
  float acc = 0.f;
  for (int i = i0; i < i1; ++i) {
    int g = batch[i];
    if (g != cur) {
      atomicAdd(&sums[cur * 64 + f], acc);
      acc = 0.f; cur = g;
    }
    acc += h[(size_t)i * 64 + f];
  }
  atomicAdd(&sums[cur * 64 + f], acc);
}

__global__ void k_pool2(const float* __restrict__ sums, const int* __restrict__ batch,
                        float* __restrict__ pooled, int n) {
  int g = blockIdx.x, f = threadIdx.x;
  int lo = 0, hi = n;
  while (lo < hi) { int m = (lo + hi) >> 1; if (batch[m] < g) lo = m + 1; else hi = m; }
  int start = lo;
  hi = n;
  while (lo < hi) { int m = (lo + hi) >> 1; if (batch[m] < g + 1) lo = m + 1; else hi = m; }
  float cnt = (float)(lo - start);
  pooled[g * 64 + f] = sums[g * 64 + f] / fmaxf(cnt, 1.f);
}

// ---------------- launch ----------------

extern "C" void kernel_launch(void* const* d_in, const int* in_sizes, int n_in,
                              void* d_out, int out_size, void* d_ws, size_t ws_size,
                              hipStream_t stream) {
  const float* x   = (const float*)d_in[0];
  const int* eidx  = (const int*)d_in[1];
  const int* batch = (const int*)d_in[2];
  const float* W1  = (const float*)d_in[3];
  const float* b1  = (const float*)d_in[4];
  const float* W2  = (const float*)d_in[5];
  const float* b2  = (const float*)d_in[6];
  const float* W3  = (const float*)d_in[7];
  const float* b3  = (const float*)d_in[8];
  float* out = (float*)d_out;

  const int n = in_sizes[0] / 7;       // 50000
  const int e = in_sizes[1] / 2;       // 800000
  const int G = out_size / 64 - n;     // 50

  // workspace carve-up (4B elements)
  float* wsf = (float*)d_ws;
  int*   wsi = (int*)d_ws;
  size_t off = 0;
  int*   deg    = wsi + off; off += n;
  float* dinv   = wsf + off; off += n;
  int*   rp     = wsi + off; off += (size_t)((n + 1 + 3) & ~3);
  int*   cursor = wsi + off; off += n;
  int*   psum   = wsi + off; off += 256;
  float* sums   = wsf + off; off += (size_t)G * 64;
  unsigned short* wb2t = (unsigned short*)(wsf + off); off += 128 * 128 / 2;  // bf16 W2^T
  unsigned short* wb3t = (unsigned short*)(wsf + off); off += 128 * 64 / 2;   // bf16 W3^T
  int*   csr    = wsi + off; off += (size_t)((e + 3) & ~3);
  float* xs     = wsf + off; off += (size_t)((n * 7 + 3) & ~3);
  float* bufA   = wsf + off; off += (size_t)n * 128;
  float* bufB   = wsf + off; off += (size_t)n * 128;

  // bf16 tensors alias fp32 buffers (dataflow strictly serialized):
  unsigned short* t2 = (unsigned short*)bufB;   // gemm1 out (dinv-scaled)
  unsigned short* a2 = (unsigned short*)bufA;   // agg128 out
  unsigned short* h2 = (unsigned short*)bufB;   // gemm2 out
  unsigned short* t3 = (unsigned short*)bufA;   // gemm3 out (dinv-scaled)

  const int* src = eidx;       // edge_index[0]
  const int* dst = eidx + e;   // edge_index[1]

  const int nb = (n + 255) / 256;

  // CSR build (real edges only, 4B entries)
  k_init_deg<<<nb, 256, 0, stream>>>(deg, n);
  k_count<<<(e + 255) / 256, 256, 0, stream>>>(dst, deg, e);
  k_dinv<<<nb, 256, 0, stream>>>(deg, dinv, n);
  k_scalex<<<(n * 7 + 255) / 256, 256, 0, stream>>>(x, dinv, xs, n);
  k_scan1<<<nb, 256, 0, stream>>>(deg, rp, psum, n);
  k_scan2<<<1, 256, 0, stream>>>(psum, nb);
  k_scan3<<<nb, 256, 0, stream>>>(rp, cursor, psum, n, e);
  k_scatter<<<(e + 255) / 256, 256, 0, stream>>>(src, dst, cursor, csr, e);
  // zero pooled sums + transpose/convert weights to bf16
  k_zero<<<(G * 64 + 255) / 256, 256, 0, stream>>>(sums, G * 64);
  k_wtr<<<(128 * 128 + 255) / 256, 256, 0, stream>>>(W2, wb2t, 128, 128);
  k_wtr<<<(128 * 64 + 255) / 256, 256, 0, stream>>>(W3, wb3t, 128, 64);

  // layer 1: AGG(xs) -> bufA fp32, then @W1 + b1, relu, dinv-scale -> bf16 t2
  k_agg7<<<((size_t)n * 64 + 255) / 256, 256, 0, stream>>>(xs, csr, rp, dinv, bufA, n);
  k_gemm1<<<(n + 1) / 2, 256, 0, stream>>>(bufA, W1, b1, dinv, t2, n);

  // layer 2: AGG(t2) -> a2 bf16, then MFMA @W2 + b2, relu -> h2 bf16
  k_agg128<<<((size_t)n * 32 + 255) / 256, 256, 0, stream>>>(t2, csr, rp, dinv, a2, n);
  k_gemm2<<<(n + 63) / 64, 256, 0, stream>>>(a2, wb2t, b2, h2, n);

  // layer 3: MFMA h2 @ W3, dinv-scale -> t3 bf16, then AGG + b3 -> d_out
  k_gemm3<<<(n + 63) / 64, 256, 0, stream>>>(h2, wb3t, dinv, t3, n);
  k_agg64b<<<((size_t)n * 16 + 255) / 256, 256, 0, stream>>>(t3, csr, rp, dinv, b3, out, n);

  // mean pool -> d_out tail (node-parallel + finalize)
  const int waves = (n + 15) / 16;
  k_pool1<<<(waves * 64 + 255) / 256, 256, 0, stream>>>(out, batch, sums, n);
  k_pool2<<<G, 64, 0, stream>>>(sums, batch, out + (size_t)n * 64, n);
}

// Round 10
// 262.727 us; speedup vs baseline: 1.0504x; 1.0504x over previous
//
#include <hip/hip_runtime.h>

typedef short s16x8 __attribute__((ext_vector_type(8)));
typedef float f32x4 __attribute__((ext_vector_type(4)));

// bf16 helpers (manual, round-to-nearest-even)
__device__ __forceinline__ unsigned short f2bf(float f) {
  unsigned int u = __float_as_uint(f);
  unsigned int r = (u + 0x7FFFu + ((u >> 16) & 1u)) >> 16;
  return (unsigned short)r;
}
__device__ __forceinline__ float bf_lo(unsigned int u) { return __uint_as_float(u << 16); }
__device__ __forceinline__ float bf_hi(unsigned int u) { return __uint_as_float(u & 0xFFFF0000u); }

// ---------------- degree / CSR build ----------------
// CSR holds REAL edges only (no self-loops), entry = src id (4 B).
// Weights factored out: rows pre-scaled by dinv[s] at producers, sums
// scaled by dinv[d] at consumers; self term added inline (coalesced).

__global__ void k_init_deg(int* __restrict__ deg, int n) {
  int i = blockIdx.x * blockDim.x + threadIdx.x;
  if (i < n) deg[i] = 1;  // self-loop counts toward degree
}

__global__ void k_count(const int* __restrict__ dst, int* __restrict__ deg, int e) {
  int i = blockIdx.x * blockDim.x + threadIdx.x;
  if (i < e) atomicAdd(&deg[dst[i]], 1);
}

__global__ void k_dinv(const int* __restrict__ deg, float* __restrict__ dinv, int n) {
  int i = blockIdx.x * blockDim.x + threadIdx.x;
  if (i < n) dinv[i] = rsqrtf((float)deg[i]);
}

// xs = x * dinv (row-wise pre-scale of input features)
__global__ void k_scalex(const float* __restrict__ x, const float* __restrict__ dinv,
                         float* __restrict__ xs, int n) {
  int i = blockIdx.x * blockDim.x + threadIdx.x;
  if (i < n * 7) xs[i] = x[i] * dinv[i / 7];
}

// scan over real-edge counts (deg-1)
__global__ void k_scan1(const int* __restrict__ deg, int* __restrict__ rp,
                        int* __restrict__ psum, int n) {
  __shared__ int s[256];
  int tid = threadIdx.x;
  int i = blockIdx.x * 256 + tid;
  int v = (i < n) ? deg[i] - 1 : 0;
  int x = v;
  s[tid] = x; __syncthreads();
  for (int off = 1; off < 256; off <<= 1) {
    int t = (tid >= off) ? s[tid - off] : 0;
    __syncthreads();
    x += t; s[tid] = x;
    __syncthreads();
  }
  if (i < n) rp[i] = x - v;                 // exclusive within block
  if (tid == 255) psum[blockIdx.x] = x;     // block total
}

__global__ void k_scan2(int* __restrict__ psum, int nb) {
  __shared__ int s[256];
  int tid = threadIdx.x;
  int v = (tid < nb) ? psum[tid] : 0;
  int x = v;
  s[tid] = x; __syncthreads();
  for (int off = 1; off < 256; off <<= 1) {
    int t = (tid >= off) ? s[tid - off] : 0;
    __syncthreads();
    x += t; s[tid] = x;
    __syncthreads();
  }
  if (tid < nb) psum[tid] = x - v;          // exclusive prefix of block sums
}

__global__ void k_scan3(int* __restrict__ rp, int* __restrict__ cursor,
                        const int* __restrict__ psum, int n, int total) {
  int i = blockIdx.x * blockDim.x + threadIdx.x;
  if (i < n) {
    int r = rp[i] + psum[i >> 8];
    rp[i] = r;
    cursor[i] = r;
  }
  if (i == 0) rp[n] = total;
}

// Windowed, XCD-affine scatter: window w = blockIdx%8 (round-robin XCD
// heuristic) owns dst in [w*wsize, (w+1)*wsize). Each window's CSR range
// (~400 KB) is written by one XCD only -> lines accumulate all 16 entries
// in that XCD's L2 before write-back (52 MB -> ~3.2 MB HBM writes).
// Cost: each chunk of the edge list is scanned by 8 blocks (L3-resident).
__global__ void k_scatter(const int* __restrict__ src, const int* __restrict__ dst,
                          int* __restrict__ cursor, int* __restrict__ csr,
                          int e, int wsize, int nchunks) {
  int w = blockIdx.x & 7;
  int c = blockIdx.x >> 3;
  int chunk = (e + nchunks - 1) / nchunks;
  int i0 = c * chunk, i1 = min(e, i0 + chunk);
  int wlo = w * wsize, whi = wlo + wsize;
  for (int i = i0 + threadIdx.x; i < i1; i += blockDim.x) {
    int d = dst[i];
    if (d >= wlo && d < whi) {
      int pos = atomicAdd(&cursor[d], 1);
      csr[pos] = src[i];
    }
  }
}

// W [K x N] fp32 -> Wt [N x K] bf16 (transposed, for contiguous B-fragment loads)
__global__ void k_wtr(const float* __restrict__ W, unsigned short* __restrict__ Wt,
                      int K, int N) {
  int i = blockIdx.x * blockDim.x + threadIdx.x;
  if (i < K * N) {
    int k = i / N, c = i - k * N;
    Wt[(size_t)c * K + k] = f2bf(W[i]);
  }
}

// ---------------- aggregation (pull, CSR by dst) ----------------

// width-7 aggregation on pre-scaled xs: lane per edge + butterfly reduce.
// out[d] = dinv[d] * (sum_{edges} xs[s] + xs[d])
__global__ void k_agg7(const float* __restrict__ xs, const int* __restrict__ csr,
                       const int* __restrict__ rp, const float* __restrict__ dinv,
                       float* __restrict__ out, int n) {
  int gid = blockIdx.x * blockDim.x + threadIdx.x;
  int v = gid >> 6, lane = gid & 63;
  if (v >= n) return;
  int beg = rp[v], end = rp[v + 1];
  float a[7] = {0.f, 0.f, 0.f, 0.f, 0.f, 0.f, 0.f};
  for (int base = beg; base < end; base += 64) {
    int cnt = end - base; if (cnt > 64) cnt = 64;
    if (lane < cnt) {
      int s = csr[base + lane];
      const float* xr = xs + (size_t)s * 7;
#pragma unroll
      for (int f = 0; f < 7; ++f) a[f] += xr[f];
    }
  }
#pragma unroll
  for (int off = 32; off > 0; off >>= 1) {
#pragma unroll
    for (int f = 0; f < 7; ++f) a[f] += __shfl_xor(a[f], off);
  }
  if (lane == 0) {
    float dv = dinv[v];
#pragma unroll
    for (int f = 0; f < 7; ++f) out[(size_t)v * 7 + f] = dv * (a[f] + xs[(size_t)v * 7 + f]);
  }
}

// width-128 bf16 aggregation: 32 lanes/node, uint2 (4 bf16)/lane.
// fp32 accumulate; out = bf16(dinv[d] * (sum + own_row)).
__global__ void k_agg128(const unsigned short* __restrict__ t, const int* __restrict__ csr,
                         const int* __restrict__ rp, const float* __restrict__ dinv,
                         unsigned short* __restrict__ out, int n) {
  int gid = blockIdx.x * blockDim.x + threadIdx.x;
  int v = gid >> 5, lane = gid & 31;
  if (v >= n) return;
  int beg = rp[v], end = rp[v + 1];
  float4 a = make_float4(0.f, 0.f, 0.f, 0.f);
  const uint2* tp = (const uint2*)t + lane;   // row stride = 32 uint2 (128 bf16)
  for (int base = beg; base < end; base += 32) {
    int cnt = end - base; if (cnt > 32) cnt = 32;
    int ee = csr[base + (lane < cnt ? lane : cnt - 1)];
    int j = 0;
    for (; j + 4 <= cnt; j += 4) {
      int s0 = __shfl(ee, j + 0, 32), s1 = __shfl(ee, j + 1, 32);
      int s2 = __shfl(ee, j + 2, 32), s3 = __shfl(ee, j + 3, 32);
      uint2 r0 = tp[(size_t)s0 * 32];
      uint2 r1 = tp[(size_t)s1 * 32];
      uint2 r2 = tp[(size_t)s2 * 32];
      uint2 r3 = tp[(size_t)s3 * 32];
      a.x += bf_lo(r0.x); a.y += bf_hi(r0.x); a.z += bf_lo(r0.y); a.w += bf_hi(r0.y);
      a.x += bf_lo(r1.x); a.y += bf_hi(r1.x); a.z += bf_lo(r1.y); a.w += bf_hi(r1.y);
      a.x += bf_lo(r2.x); a.y += bf_hi(r2.x); a.z += bf_lo(r2.y); a.w += bf_hi(r2.y);
      a.x += bf_lo(r3.x); a.y += bf_hi(r3.x); a.z += bf_lo(r3.y); a.w += bf_hi(r3.y);
    }
    for (; j < cnt; ++j) {
      int s0 = __shfl(ee, j, 32);
      uint2 r0 = tp[(size_t)s0 * 32];
      a.x += bf_lo(r0.x); a.y += bf_hi(r0.x); a.z += bf_lo(r0.y); a.w += bf_hi(r0.y);
    }
  }
  // self term (coalesced)
  {
    uint2 r = tp[(size_t)v * 32];
    a.x += bf_lo(r.x); a.y += bf_hi(r.x); a.z += bf_lo(r.y); a.w += bf_hi(r.y);
  }
  float dv = dinv[v];
  unsigned int lo = (unsigned int)f2bf(a.x * dv) | ((unsigned int)f2bf(a.y * dv) << 16);
  unsigned int hi = (unsigned int)f2bf(a.z * dv) | ((unsigned int)f2bf(a.w * dv) << 16);
  ((uint2*)(out + (size_t)v * 128))[lane] = make_uint2(lo, hi);
}

// width-64 bf16 aggregation + bias: 16 lanes/node.
// out[d] = dinv[d] * (sum + own_row) + b3  (fp32 out)
__global__ void k_agg64b(const unsigned short* __restrict__ t, const int* __restrict__ csr,
                         const int* __restrict__ rp, const float* __restrict__ dinv,
                         const float* __restrict__ bias, float* __restrict__ out, int n) {
  int gid = blockIdx.x * blockDim.x + threadIdx.x;
  int v = gid >> 4, lane = gid & 15;
  if (v >= n) return;
  int beg = rp[v], end = rp[v + 1];
  float4 a = make_float4(0.f, 0.f, 0.f, 0.f);
  const uint2* tp = (const uint2*)t + lane;   // row stride = 16 uint2 (64 bf16)
  for (int base = beg; base < end; base += 16) {
    int cnt = end - base; if (cnt > 16) cnt = 16;
    int ee = csr[base + (lane < cnt ? lane : cnt - 1)];
    int j = 0;
    for (; j + 4 <= cnt; j += 4) {
      int s0 = __shfl(ee, j + 0, 16), s1 = __shfl(ee, j + 1, 16);
      int s2 = __shfl(ee, j + 2, 16), s3 = __shfl(ee, j + 3, 16);
      uint2 r0 = tp[(size_t)s0 * 16];
      uint2 r1 = tp[(size_t)s1 * 16];
      uint2 r2 = tp[(size_t)s2 * 16];
      uint2 r3 = tp[(size_t)s3 * 16];
      a.x += bf_lo(r0.x); a.y += bf_hi(r0.x); a.z += bf_lo(r0.y); a.w += bf_hi(r0.y);
      a.x += bf_lo(r1.x); a.y += bf_hi(r1.x); a.z += bf_lo(r1.y); a.w += bf_hi(r1.y);
      a.x += bf_lo(r2.x); a.y += bf_hi(r2.x); a.z += bf_lo(r2.y); a.w += bf_hi(r2.y);
      a.x += bf_lo(r3.x); a.y += bf_hi(r3.x); a.z += bf_lo(r3.y); a.w += bf_hi(r3.y);
    }
    for (; j < cnt; ++j) {
      int s0 = __shfl(ee, j, 16);
      uint2 r0 = tp[(size_t)s0 * 16];
      a.x += bf_lo(r0.x); a.y += bf_hi(r0.x); a.z += bf_lo(r0.y); a.w += bf_hi(r0.y);
    }
  }
  // self term (coalesced)
  {
    uint2 r = tp[(size_t)v * 16];
    a.x += bf_lo(r.x); a.y += bf_hi(r.x); a.z += bf_lo(r.y); a.w += bf_hi(r.y);
  }
  float dv = dinv[v];
  const float4 b4 = ((const float4*)bias)[lane];
  a.x = a.x * dv + b4.x; a.y = a.y * dv + b4.y;
  a.z = a.z * dv + b4.z; a.w = a.w * dv + b4.w;
  ((float4*)(out + (size_t)v * 64))[lane] = a;
}

// ---------------- GEMMs ----------------

// [n,7] @ [7,128] + b, relu, then row-scale by dinv -> bf16 out.
__global__ __launch_bounds__(256) void k_gemm1(const float* __restrict__ A,
                                               const float* __restrict__ W,
                                               const float* __restrict__ bias,
                                               const float* __restrict__ dinv,
                                               unsigned short* __restrict__ out, int n) {
  __shared__ float ws[7 * 128];
  for (int j = threadIdx.x; j < 7 * 128; j += 256) ws[j] = W[j];
  __syncthreads();
  int r = blockIdx.x * 2 + (threadIdx.x >> 7);
  int c = threadIdx.x & 127;
  if (r >= n) return;
  const float* a = A + (size_t)r * 7;
  float acc = bias[c];
#pragma unroll
  for (int k = 0; k < 7; ++k) acc += a[k] * ws[k * 128 + c];
  out[(size_t)r * 128 + c] = f2bf(fmaxf(acc, 0.f) * dinv[r]);
}

// MFMA gemm2: [n,128]bf16 @ W2 + b2, relu -> [n,128]bf16.
__global__ __launch_bounds__(256) void k_gemm2(const unsigned short* __restrict__ A,
                                               const unsigned short* __restrict__ Bt,
                                               const float* __restrict__ bias,
                                               unsigned short* __restrict__ out, int n) {
  int wave = threadIdx.x >> 6, lane = threadIdx.x & 63;
  int am = lane & 15, kg = lane >> 4;
  int r0 = blockIdx.x * 64 + wave * 16;
  int arow = min(r0 + am, n - 1);
  const unsigned short* ap = A + (size_t)arow * 128 + kg * 8;
  f32x4 acc[8] = {};
#pragma unroll
  for (int kb = 0; kb < 4; ++kb) {
    s16x8 a = *(const s16x8*)(ap + kb * 32);
#pragma unroll
    for (int c = 0; c < 8; ++c) {
      s16x8 b = *(const s16x8*)(Bt + (size_t)(c * 16 + am) * 128 + kb * 32 + kg * 8);
      acc[c] = __builtin_amdgcn_mfma_f32_16x16x32_bf16(a, b, acc[c], 0, 0, 0);
    }
  }
#pragma unroll
  for (int c = 0; c < 8; ++c) {
    float bb = bias[c * 16 + am];
#pragma unroll
    for (int j = 0; j < 4; ++j) {
      int r = r0 + kg * 4 + j;
      if (r < n) out[(size_t)r * 128 + c * 16 + am] = f2bf(fmaxf(acc[c][j] + bb, 0.f));
    }
  }
}

// MFMA gemm3: [n,128]bf16 @ W3, row-scale by dinv -> [n,64]bf16 (feeds agg64b).
__global__ __launch_bounds__(256) void k_gemm3(const unsigned short* __restrict__ A,
                                               const unsigned short* __restrict__ Bt,
                                               const float* __restrict__ dinv,
                                               unsigned short* __restrict__ out, int n) {
  int wave = threadIdx.x >> 6, lane = threadIdx.x & 63;
  int am = lane & 15, kg = lane >> 4;
  int r0 = blockIdx.x * 64 + wave * 16;
  int arow = min(r0 + am, n - 1);
  const unsigned short* ap = A + (size_t)arow * 128 + kg * 8;
  f32x4 acc[4] = {};
#pragma unroll
  for (int kb = 0; kb < 4; ++kb) {
    s16x8 a = *(const s16x8*)(ap + kb * 32);
#pragma unroll
    for (int c = 0; c < 4; ++c) {
      s16x8 b = *(const s16x8*)(Bt + (size_t)(c * 16 + am) * 128 + kb * 32 + kg * 8);
      acc[c] = __builtin_amdgcn_mfma_f32_16x16x32_bf16(a, b, acc[c], 0, 0, 0);
    }
  }
  float dv[4];
#pragma unroll
  for (int j = 0; j < 4; ++j) dv[j] = dinv[min(r0 + kg * 4 + j, n - 1)];
#pragma unroll
  for (int c = 0; c < 4; ++c) {
#pragma unroll
    for (int j = 0; j < 4; ++j) {
      int r = r0 + kg * 4 + j;
      if (r < n) out[(size_t)r * 64 + c * 16 + am] = f2bf(acc[c][j] * dv[j]);
    }
  }
}

// ---------------- mean pool over sorted batch (node-parallel) ----------------

__global__ void k_zero(float* __restrict__ p, int n) {
  int i = blockIdx.x * blockDim.x + threadIdx.x;
  if (i < n) p[i] = 0.f;
}

__global__ void k_pool1(const float* __restrict__ h, const int* __restrict__ batch,
                        float* __restrict__ sums, int n) {
  int gid = blockIdx.x * blockDim.x + threadIdx.x;
  int w = gid >> 6, f = gid & 63;
  int i0 = w * 16;
  if (i0 >= n) return;
  int i1 = min(i0 + 16, n);
  int cur = batch[i0];
  float acc = 0.f;
  for (int i = i0; i < i1; ++i) {
    int g = batch[i];
    if (g != cur) {
      atomicAdd(&sums[cur * 64 + f], acc);
      acc = 0.f; cur = g;
    }
    acc += h[(size_t)i * 64 + f];
  }
  atomicAdd(&sums[cur * 64 + f], acc);
}

__global__ void k_pool2(const float* __restrict__ sums, const int* __restrict__ batch,
                        float* __restrict__ pooled, int n) {
  int g = blockIdx.x, f = threadIdx.x;
  int lo = 0, hi = n;
  while (lo < hi) { int m = (lo + hi) >> 1; if (batch[m] < g) lo = m + 1; else hi = m; }
  int start = lo;
  hi = n;
  while (lo < hi) { int m = (lo + hi) >> 1; if (batch[m] < g + 1) lo = m + 1; else hi = m; }
  float cnt = (float)(lo - start);
  pooled[g * 64 + f] = sums[g * 64 + f] / fmaxf(cnt, 1.f);
}

// ---------------- launch ----------------

extern "C" void kernel_launch(void* const* d_in, const int* in_sizes, int n_in,
                              void* d_out, int out_size, void* d_ws, size_t ws_size,
                              hipStream_t stream) {
  const float* x   = (const float*)d_in[0];
  const int* eidx  = (const int*)d_in[1];
  const int* batch = (const int*)d_in[2];
  const float* W1  = (const float*)d_in[3];
  const float* b1  = (const float*)d_in[4];
  const float* W2  = (const float*)d_in[5];
  const float* b2  = (const float*)d_in[6];
  const float* W3  = (const float*)d_in[7];
  const float* b3  = (const float*)d_in[8];
  float* out = (float*)d_out;

  const int n = in_sizes[0] / 7;       // 50000
  const int e = in_sizes[1] / 2;       // 800000
  const int G = out_size / 64 - n;     // 50

  // workspace carve-up (4B elements)
  float* wsf = (float*)d_ws;
  int*   wsi = (int*)d_ws;
  size_t off = 0;
  int*   deg    = wsi + off; off += n;
  float* dinv   = wsf + off; off += n;
  int*   rp     = wsi + off; off += (size_t)((n + 1 + 3) & ~3);
  int*   cursor = wsi + off; off += n;
  int*   psum   = wsi + off; off += 256;
  float* sums   = wsf + off; off += (size_t)G * 64;
  unsigned short* wb2t = (unsigned short*)(wsf + off); off += 128 * 128 / 2;  // bf16 W2^T
  unsigned short* wb3t = (unsigned short*)(wsf + off); off += 128 * 64 / 2;   // bf16 W3^T
  int*   csr    = wsi + off; off += (size_t)((e + 3) & ~3);
  float* xs     = wsf + off; off += (size_t)((n * 7 + 3) & ~3);
  float* bufA   = wsf + off; off += (size_t)n * 128;
  float* bufB   = wsf + off; off += (size_t)n * 128;

  // bf16 tensors alias fp32 buffers (dataflow strictly serialized):
  unsigned short* t2 = (unsigned short*)bufB;   // gemm1 out (dinv-scaled)
  unsigned short* a2 = (unsigned short*)bufA;   // agg128 out
  unsigned short* h2 = (unsigned short*)bufB;   // gemm2 out
  unsigned short* t3 = (unsigned short*)bufA;   // gemm3 out (dinv-scaled)

  const int* src = eidx;       // edge_index[0]
  const int* dst = eidx + e;   // edge_index[1]

  const int nb = (n + 255) / 256;

  // CSR build (real edges only, 4B entries; windowed XCD-affine scatter)
  k_init_deg<<<nb, 256, 0, stream>>>(deg, n);
  k_count<<<(e + 255) / 256, 256, 0, stream>>>(dst, deg, e);
  k_dinv<<<nb, 256, 0, stream>>>(deg, dinv, n);
  k_scalex<<<(n * 7 + 255) / 256, 256, 0, stream>>>(x, dinv, xs, n);
  k_scan1<<<nb, 256, 0, stream>>>(deg, rp, psum, n);
  k_scan2<<<1, 256, 0, stream>>>(psum, nb);
  k_scan3<<<nb, 256, 0, stream>>>(rp, cursor, psum, n, e);
  const int nchunks = 128;
  const int wsize = (n + 7) / 8;
  k_scatter<<<8 * nchunks, 256, 0, stream>>>(src, dst, cursor, csr, e, wsize, nchunks);
  // zero pooled sums + transpose/convert weights to bf16
  k_zero<<<(G * 64 + 255) / 256, 256, 0, stream>>>(sums, G * 64);
  k_wtr<<<(128 * 128 + 255) / 256, 256, 0, stream>>>(W2, wb2t, 128, 128);
  k_wtr<<<(128 * 64 + 255) / 256, 256, 0, stream>>>(W3, wb3t, 128, 64);

  // layer 1: AGG(xs) -> bufA fp32, then @W1 + b1, relu, dinv-scale -> bf16 t2
  k_agg7<<<((size_t)n * 64 + 255) / 256, 256, 0, stream>>>(xs, csr, rp, dinv, bufA, n);
  k_gemm1<<<(n + 1) / 2, 256, 0, stream>>>(bufA, W1, b1, dinv, t2, n);

  // layer 2: AGG(t2) -> a2 bf16, then MFMA @W2 + b2, relu -> h2 bf16
  k_agg128<<<((size_t)n * 32 + 255) / 256, 256, 0, stream>>>(t2, csr, rp, dinv, a2, n);
  k_gemm2<<<(n + 63) / 64, 256, 0, stream>>>(a2, wb2t, b2, h2, n);

  // layer 3: MFMA h2 @ W3, dinv-scale -> t3 bf16, then AGG + b3 -> d_out
  k_gemm3<<<(n + 63) / 64, 256, 0, stream>>>(h2, wb3t, dinv, t3, n);
  k_agg64b<<<((size_t)n * 16 + 255) / 256, 256, 0, stream>>>(t3, csr, rp, dinv, b3, out, n);

  // mean pool -> d_out tail (node-parallel + finalize)
  const int waves = (n + 15) / 16;
  k_pool1<<<(waves * 64 + 255) / 256, 256, 0, stream>>>(out, batch, sums, n);
  k_pool2<<<G, 64, 0, stream>>>(sums, batch, out + (size_t)n * 64, n);
}